// Round 1
// baseline (1592.454 us; speedup 1.0000x reference)
//
#include <hip/hip_runtime.h>
#include <hip/hip_bf16.h>

// CrossNetMoE: L=3 layers, E=4 experts, D=1024, R=64, B=16384. All f32.
// Per layer (folding gate into expert sum, sum_e g = 1):
//   v = tanh(V_e @ xl)             [B,E,R]
//   c = tanh(C_e @ v)              [B,E,R]
//   out = b + sum_e g_e*(U_e @ c)  [B,D],  g = softmax(Wg_e . xl)
//   xl' = tanh(out*x0 + xl)  (layers 0,1) / out*x0 + xl (layer 2)
//
// Fused per-layer kernel; each workgroup owns BT=32 batch rows end-to-end.
// d_out is used as the xl ping buffer (in-place safe: rows are private to a
// workgroup and each epilogue element is read-then-written by one thread).

#define B_TOT 16384
#define DDIM  1024
#define RLOW  64
#define NEXP  4
#define NLAY  3
#define BT    32
#define KC    64

__global__ __launch_bounds__(256) void cross_layer_f32(
    const float* __restrict__ xsrc, float* __restrict__ xdst,
    const float* __restrict__ x0,
    const float* __restrict__ U, const float* __restrict__ V,
    const float* __restrict__ C, const float* __restrict__ Wg,
    const float* __restrict__ bias, const int do_tanh)
{
    __shared__ float s_x[BT][KC];        // xl chunk        (8 KB)
    __shared__ float s_p[BT][264];       // v then g*c      (33.8 KB, 264 stride)
    __shared__ float s_g[BT][NEXP];      // gate            (0.5 KB)

    const int tid  = threadIdx.x;
    const int row0 = blockIdx.x * BT;

    // ---------------- Phase 1: v[b, n] = tanh(sum_d V[n,d]*xl[b,d]), n = tid
    float acc[BT];
#pragma unroll
    for (int i = 0; i < BT; ++i) acc[i] = 0.f;

    const float* vrow = V + (size_t)tid * DDIM;   // V[e,r,:] with n = e*64+r = tid
    for (int kc = 0; kc < DDIM; kc += KC) {
#pragma unroll
        for (int j = 0; j < (BT * KC) / 256; ++j) {
            int i = tid + j * 256;
            s_x[i >> 6][i & 63] = xsrc[(size_t)(row0 + (i >> 6)) * DDIM + kc + (i & 63)];
        }
        __syncthreads();
#pragma unroll 4
        for (int k = 0; k < KC; k += 4) {
            float4 w = *reinterpret_cast<const float4*>(vrow + kc + k);
#pragma unroll
            for (int rr = 0; rr < BT; ++rr) {
                float4 xv = *reinterpret_cast<const float4*>(&s_x[rr][k]);
                acc[rr] = fmaf(w.x, xv.x, acc[rr]);
                acc[rr] = fmaf(w.y, xv.y, acc[rr]);
                acc[rr] = fmaf(w.z, xv.z, acc[rr]);
                acc[rr] = fmaf(w.w, xv.w, acc[rr]);
            }
        }
        __syncthreads();
    }
#pragma unroll
    for (int rr = 0; rr < BT; ++rr) s_p[rr][tid] = tanhf(acc[rr]);

    // ---------------- Phase 1b: gate g = softmax_e(Wg_e . xl)  (128 threads)
    if (tid < BT * NEXP) {
        const int rr = tid >> 2, e = tid & 3;
        const float* wg = Wg + (size_t)e * DDIM;
        const float* xr = xsrc + (size_t)(row0 + rr) * DDIM;
        float s = 0.f;
        for (int d = 0; d < DDIM; d += 4) {
            float4 a  = *reinterpret_cast<const float4*>(wg + d);
            float4 xv = *reinterpret_cast<const float4*>(xr + d);
            s = fmaf(a.x, xv.x, s); s = fmaf(a.y, xv.y, s);
            s = fmaf(a.z, xv.z, s); s = fmaf(a.w, xv.w, s);
        }
        float m = s;
        m = fmaxf(m, __shfl_xor(m, 1));
        m = fmaxf(m, __shfl_xor(m, 2));
        float ex  = expf(s - m);
        float sum = ex;
        sum += __shfl_xor(sum, 1);
        sum += __shfl_xor(sum, 2);
        s_g[rr][e] = ex / sum;
    }
    __syncthreads();

    // ---------------- Phase 2: p[b, n] = g[b,e]*tanh(sum_s C[e,r,s]*v[b,e,s])
    {
        const int e = tid >> 6, r = tid & 63;
        const float* crow = C + (size_t)(e * RLOW + r) * RLOW;
        float cacc[BT];
#pragma unroll
        for (int rr = 0; rr < BT; ++rr) cacc[rr] = 0.f;
#pragma unroll 4
        for (int s4 = 0; s4 < RLOW; s4 += 4) {
            float4 cw = *reinterpret_cast<const float4*>(crow + s4);
#pragma unroll
            for (int rr = 0; rr < BT; ++rr) {
                float4 vv = *reinterpret_cast<const float4*>(&s_p[rr][e * RLOW + s4]);
                cacc[rr] = fmaf(cw.x, vv.x, cacc[rr]);
                cacc[rr] = fmaf(cw.y, vv.y, cacc[rr]);
                cacc[rr] = fmaf(cw.z, vv.z, cacc[rr]);
                cacc[rr] = fmaf(cw.w, vv.w, cacc[rr]);
            }
        }
        __syncthreads();   // all v reads complete before overwrite
#pragma unroll
        for (int rr = 0; rr < BT; ++rr)
            s_p[rr][tid] = tanhf(cacc[rr]) * s_g[rr][e];
    }
    __syncthreads();

    // ---------------- Phase 3: out[b,d] = bias[d] + sum_k U[k-col d]*p[b,k]
    //                  then xl' = (out*x0 + xl) [tanh]
#pragma unroll 1
    for (int pass = 0; pass < 4; ++pass) {
        const int d = pass * 256 + tid;
        float oacc[BT];
#pragma unroll
        for (int rr = 0; rr < BT; ++rr) oacc[rr] = 0.f;
#pragma unroll 1
        for (int e = 0; e < NEXP; ++e) {
            const float* up = U + ((size_t)e * DDIM + d) * RLOW;  // U[e,d,:]
#pragma unroll 4
            for (int r4 = 0; r4 < RLOW; r4 += 4) {
                float4 uw = *reinterpret_cast<const float4*>(up + r4);
                const int k = e * RLOW + r4;
#pragma unroll
                for (int rr = 0; rr < BT; ++rr) {
                    float4 pv = *reinterpret_cast<const float4*>(&s_p[rr][k]);
                    oacc[rr] = fmaf(uw.x, pv.x, oacc[rr]);
                    oacc[rr] = fmaf(uw.y, pv.y, oacc[rr]);
                    oacc[rr] = fmaf(uw.z, pv.z, oacc[rr]);
                    oacc[rr] = fmaf(uw.w, pv.w, oacc[rr]);
                }
            }
        }
        const float bd = bias[d];
#pragma unroll
        for (int rr = 0; rr < BT; ++rr) {
            const size_t idx = (size_t)(row0 + rr) * DDIM + d;
            float y = fmaf(oacc[rr] + bd, x0[idx], xsrc[idx]);
            if (do_tanh) y = tanhf(y);
            xdst[idx] = y;
        }
    }
}

extern "C" void kernel_launch(void* const* d_in, const int* in_sizes, int n_in,
                              void* d_out, int out_size, void* d_ws, size_t ws_size,
                              hipStream_t stream)
{
    const float* x  = (const float*)d_in[0];
    const float* U  = (const float*)d_in[1];
    const float* V  = (const float*)d_in[2];
    const float* C  = (const float*)d_in[3];
    const float* Wg = (const float*)d_in[4];
    const float* bb = (const float*)d_in[5];
    float* out = (float*)d_out;

    const size_t sU = (size_t)NEXP * DDIM * RLOW;   // 262144
    const size_t sV = (size_t)NEXP * RLOW * DDIM;   // 262144
    const size_t sC = (size_t)NEXP * RLOW * RLOW;   // 16384
    const size_t sW = (size_t)NEXP * DDIM;          // 4096
    const size_t sB = (size_t)DDIM;                 // 1024

    dim3 grid(B_TOT / BT), block(256);
    for (int l = 0; l < NLAY; ++l) {
        const float* src = (l == 0) ? x : out;
        cross_layer_f32<<<grid, block, 0, stream>>>(
            src, out, x,
            U + (size_t)l * sU, V + (size_t)l * sV, C + (size_t)l * sC,
            Wg + (size_t)l * sW, bb + (size_t)l * sB,
            (l < NLAY - 1) ? 1 : 0);
    }
}

// Round 2
// 485.438 us; speedup vs baseline: 3.2804x; 3.2804x over previous
//
#include <hip/hip_runtime.h>
#include <hip/hip_bf16.h>

// CrossNetMoE via f16 MFMA. L=3, E=4, D=1024, R=64, B=16384.
// Per layer: v=tanh(V_e@xl); c=tanh(C_e@v); out=b+sum_e g_e*(U_e@c);
//            xl' = [tanh](out*x0 + xl)
// Weights pre-cast to f16 in d_ws. Each WG owns BT=32 batch rows end-to-end.
// MFMA 16x16x32_f16: A/B frag: lane l elem j -> k = 8*(l/16)+j (same mapping
// both operands => correct for any bijection). D: col=lane&15,
// row=4*(lane>>4)+reg  [learn_hip m89].

typedef _Float16 f16;
typedef f16  f16x4 __attribute__((ext_vector_type(4)));
typedef f16  f16x8 __attribute__((ext_vector_type(8)));
typedef float f32x4 __attribute__((ext_vector_type(4)));

#define B_TOT 16384
#define DDIM  1024
#define RLOW  64
#define NEXP  4
#define NLAY  3
#define BT    32
#define SPAD  264   // 256 + 8 f16 pad (528B row stride -> balanced banks)

__device__ __forceinline__ float ftanh(float x) {
    float e2 = __expf(2.0f * x);          // v_exp_f32 based, saturates to +-1
    return 1.0f - 2.0f / (e2 + 1.0f);
}

__device__ __forceinline__ f32x4 mfma16(f16x8 a, f16x8 b, f32x4 c) {
    return __builtin_amdgcn_mfma_f32_16x16x32_f16(a, b, c, 0, 0, 0);
}

__global__ void cast_f32_to_f16(const float* __restrict__ in,
                                f16* __restrict__ out, int n4) {
    int i = blockIdx.x * 256 + threadIdx.x;
    if (i < n4) {
        float4 v = reinterpret_cast<const float4*>(in)[i];
        f16x4 h;
        h.x = (f16)v.x; h.y = (f16)v.y; h.z = (f16)v.z; h.w = (f16)v.w;
        reinterpret_cast<f16x4*>(out)[i] = h;
    }
}

__global__ __launch_bounds__(256) void cross_layer_mfma(
    const float* __restrict__ xsrc, float* __restrict__ xdst,
    const float* __restrict__ x0,
    const f16* __restrict__ Uh,   // [E][D][R]
    const f16* __restrict__ Vh,   // [256][1024]  (n=e*64+r, k)
    const f16* __restrict__ Ch,   // [E][64][64]  (r, s)
    const float* __restrict__ Wg, const float* __restrict__ bias,
    const int do_tanh)
{
    __shared__ f16  s_a[BT][SPAD];   // xl f16 chunk; later p = g*tanh(c)
    __shared__ f16  s_v[BT][SPAD];   // v = tanh(V@xl)
    __shared__ float s_g[BT][NEXP];

    const int tid  = threadIdx.x;
    const int lane = tid & 63;
    const int wv   = tid >> 6;       // wave 0..3
    const int l16  = lane & 15;
    const int lhi  = lane >> 4;      // 0..3
    const int row0 = blockIdx.x * BT;

    // ================= GEMM-1: v = tanh(xl @ V^T), wave wv owns n in [wv*64, wv*64+64)
    f32x4 acc1[2][4];
#pragma unroll
    for (int i = 0; i < 2; ++i)
#pragma unroll
        for (int j = 0; j < 4; ++j) acc1[i][j] = (f32x4){0.f, 0.f, 0.f, 0.f};

    const f16* Vbase = Vh + ((size_t)(wv * 64 + l16)) * DDIM + lhi * 8;

#pragma unroll 1
    for (int c = 0; c < 4; ++c) {                 // K chunks of 256
        __syncthreads();                          // prior s_a reads complete
#pragma unroll
        for (int j = 0; j < 8; ++j) {             // stage xl chunk -> f16 LDS
            int f = tid + j * 256;                // 0..2047
            int row = f >> 6, kg = f & 63;
            float4 xv = *reinterpret_cast<const float4*>(
                xsrc + (size_t)(row0 + row) * DDIM + c * 256 + kg * 4);
            f16x4 h;
            h.x = (f16)xv.x; h.y = (f16)xv.y; h.z = (f16)xv.z; h.w = (f16)xv.w;
            *reinterpret_cast<f16x4*>(&s_a[row][kg * 4]) = h;
        }
        __syncthreads();
#pragma unroll
        for (int kt = 0; kt < 8; ++kt) {          // k-tiles of 32
            f16x8 af0 = *reinterpret_cast<const f16x8*>(&s_a[l16][kt * 32 + lhi * 8]);
            f16x8 af1 = *reinterpret_cast<const f16x8*>(&s_a[16 + l16][kt * 32 + lhi * 8]);
#pragma unroll
            for (int nt = 0; nt < 4; ++nt) {
                f16x8 bf = *reinterpret_cast<const f16x8*>(
                    Vbase + (size_t)nt * 16 * DDIM + c * 256 + kt * 32);
                acc1[0][nt] = mfma16(af0, bf, acc1[0][nt]);
                acc1[1][nt] = mfma16(af1, bf, acc1[1][nt]);
            }
        }
    }
#pragma unroll
    for (int mt = 0; mt < 2; ++mt)
#pragma unroll
        for (int nt = 0; nt < 4; ++nt)
#pragma unroll
            for (int r = 0; r < 4; ++r) {
                int row = mt * 16 + lhi * 4 + r;
                int col = wv * 64 + nt * 16 + l16;
                s_v[row][col] = (f16)ftanh(acc1[mt][nt][r]);
            }

    // ================= gate: g = softmax_e(Wg_e . xl)   (all 256 threads)
    {
        const int rr = tid >> 3;          // 0..31
        const int e  = (tid >> 1) & 3;
        const int h  = tid & 1;
        const float* wg = Wg + (size_t)e * DDIM + h * 512;
        const float* xr = xsrc + (size_t)(row0 + rr) * DDIM + h * 512;
        float s = 0.f;
#pragma unroll 4
        for (int d = 0; d < 512; d += 4) {
            float4 a  = *reinterpret_cast<const float4*>(wg + d);
            float4 xv = *reinterpret_cast<const float4*>(xr + d);
            s = fmaf(a.x, xv.x, s); s = fmaf(a.y, xv.y, s);
            s = fmaf(a.z, xv.z, s); s = fmaf(a.w, xv.w, s);
        }
        s += __shfl_xor(s, 1);            // combine halves
        float m = s;
        m = fmaxf(m, __shfl_xor(m, 2));   // reduce over expert bits
        m = fmaxf(m, __shfl_xor(m, 4));
        float ex = __expf(s - m);
        float sum = ex;
        sum += __shfl_xor(sum, 2);
        sum += __shfl_xor(sum, 4);
        if (h == 0) s_g[rr][e] = ex / sum;
    }
    __syncthreads();   // v, s_g visible; s_a free for p

    // ================= GEMM-2: p = g_e * tanh(C_e @ v), wave wv = expert wv
    {
        const int e = wv;
        f32x4 acc2[2][4];
#pragma unroll
        for (int i = 0; i < 2; ++i)
#pragma unroll
            for (int j = 0; j < 4; ++j) acc2[i][j] = (f32x4){0.f, 0.f, 0.f, 0.f};
        const f16* Cbase = Ch + ((size_t)(e * 64 + l16)) * RLOW + lhi * 8;
#pragma unroll
        for (int kt = 0; kt < 2; ++kt) {
            f16x8 af0 = *reinterpret_cast<const f16x8*>(&s_v[l16][e * 64 + kt * 32 + lhi * 8]);
            f16x8 af1 = *reinterpret_cast<const f16x8*>(&s_v[16 + l16][e * 64 + kt * 32 + lhi * 8]);
#pragma unroll
            for (int nt = 0; nt < 4; ++nt) {
                f16x8 bf = *reinterpret_cast<const f16x8*>(Cbase + (size_t)nt * 16 * RLOW + kt * 32);
                acc2[0][nt] = mfma16(af0, bf, acc2[0][nt]);
                acc2[1][nt] = mfma16(af1, bf, acc2[1][nt]);
            }
        }
#pragma unroll
        for (int mt = 0; mt < 2; ++mt)
#pragma unroll
            for (int nt = 0; nt < 4; ++nt)
#pragma unroll
                for (int r = 0; r < 4; ++r) {
                    int row = mt * 16 + lhi * 4 + r;
                    int col = nt * 16 + l16;
                    s_a[row][e * 64 + col] = (f16)(ftanh(acc2[mt][nt][r]) * s_g[row][e]);
                }
    }
    __syncthreads();

    // ================= GEMM-3: out = p @ Ut, wave wv owns d in [wv*256, wv*256+256)
#pragma unroll 1
    for (int ps = 0; ps < 4; ++ps) {
        f32x4 acc3[2][4];
#pragma unroll
        for (int i = 0; i < 2; ++i)
#pragma unroll
            for (int j = 0; j < 4; ++j) acc3[i][j] = (f32x4){0.f, 0.f, 0.f, 0.f};
        const int dbase = wv * 256 + ps * 64;
#pragma unroll
        for (int kt = 0; kt < 8; ++kt) {
            f16x8 af0 = *reinterpret_cast<const f16x8*>(&s_a[l16][kt * 32 + lhi * 8]);
            f16x8 af1 = *reinterpret_cast<const f16x8*>(&s_a[16 + l16][kt * 32 + lhi * 8]);
            const int e  = kt >> 1;
            const int r0 = (kt & 1) * 32 + lhi * 8;
#pragma unroll
            for (int nt = 0; nt < 4; ++nt) {
                const f16* bp = Uh + ((size_t)e * DDIM + dbase + nt * 16 + l16) * RLOW + r0;
                f16x8 bf = *reinterpret_cast<const f16x8*>(bp);
                acc3[0][nt] = mfma16(af0, bf, acc3[0][nt]);
                acc3[1][nt] = mfma16(af1, bf, acc3[1][nt]);
            }
        }
#pragma unroll
        for (int nt = 0; nt < 4; ++nt) {
            const int d = dbase + nt * 16 + l16;
            const float bd = bias[d];
#pragma unroll
            for (int mt = 0; mt < 2; ++mt)
#pragma unroll
                for (int r = 0; r < 4; ++r) {
                    const int m = mt * 16 + lhi * 4 + r;
                    const size_t idx = (size_t)(row0 + m) * DDIM + d;
                    float y = fmaf(acc3[mt][nt][r] + bd, x0[idx], xsrc[idx]);
                    if (do_tanh) y = ftanh(y);
                    xdst[idx] = y;
                }
        }
    }
}

extern "C" void kernel_launch(void* const* d_in, const int* in_sizes, int n_in,
                              void* d_out, int out_size, void* d_ws, size_t ws_size,
                              hipStream_t stream)
{
    const float* x  = (const float*)d_in[0];
    const float* U  = (const float*)d_in[1];
    const float* V  = (const float*)d_in[2];
    const float* C  = (const float*)d_in[3];
    const float* Wg = (const float*)d_in[4];
    const float* bb = (const float*)d_in[5];
    float* out = (float*)d_out;

    const size_t sUV = (size_t)NEXP * DDIM * RLOW;          // 262144 per layer
    const size_t sC  = (size_t)NEXP * RLOW * RLOW;          // 16384  per layer

    f16* Vh = (f16*)d_ws;                                   // [3][256][1024]
    f16* Uh = Vh + NLAY * sUV;                              // [3][E][D][R]
    f16* Ch = Uh + NLAY * sUV;                              // [3][E][64][64]

    {   // one-time (per launch) weight casts, ~3.2 MB total
        int n4v = (int)(NLAY * sUV / 4);
        cast_f32_to_f16<<<(n4v + 255) / 256, 256, 0, stream>>>(V, Vh, n4v);
        cast_f32_to_f16<<<(n4v + 255) / 256, 256, 0, stream>>>(U, Uh, n4v);
        int n4c = (int)(NLAY * sC / 4);
        cast_f32_to_f16<<<(n4c + 255) / 256, 256, 0, stream>>>(C, Ch, n4c);
    }

    dim3 grid(B_TOT / BT), block(256);
    for (int l = 0; l < NLAY; ++l) {
        const float* src = (l == 0) ? x : out;
        cross_layer_mfma<<<grid, block, 0, stream>>>(
            src, out, x,
            Uh + (size_t)l * sUV, Vh + (size_t)l * sUV, Ch + (size_t)l * sC,
            Wg + (size_t)l * NEXP * DDIM, bb + (size_t)l * DDIM,
            (l < NLAY - 1) ? 1 : 0);
    }
}

// Round 3
// 426.349 us; speedup vs baseline: 3.7351x; 1.1386x over previous
//
#include <hip/hip_runtime.h>
#include <hip/hip_bf16.h>

// CrossNetMoE fully fused: all 3 layers in one kernel, xl resident in LDS.
// L=3, E=4, D=1024, R=64, B=16384. Rows are independent across the entire
// network -> each WG owns BT=16 rows end-to-end. Global traffic = read x
// (64MB) + write out (64MB) + L2-resident f16 weights.
// Gate is folded into GEMM-1 as an extra MFMA N-tile (zero-padded Wg).
// MFMA 16x16x32_f16; A/B frag k-map: k = 8*(lane>>4)+j (same both operands);
// D: col=lane&15, row=4*(lane>>4)+reg [learn_hip m89].

typedef _Float16 f16;
typedef f16  f16x8 __attribute__((ext_vector_type(8)));
typedef float f32x4 __attribute__((ext_vector_type(4)));

#define B_TOT 16384
#define DDIM  1024
#define RLOW  64
#define NEXP  4
#define NLAY  3
#define BT    16
#define XPAD  1032   // 1024 + 8 f16 pad: row stride 2064B = 516 dw = +4 banks/row
#define SPAD  264    // 256 + 8 f16 pad:  row stride 528B  = 132 dw = +4 banks/row

__device__ __forceinline__ float ftanh(float x) {
    float e2 = __expf(2.0f * x);          // saturates correctly at +-inf
    return 1.0f - 2.0f / (e2 + 1.0f);
}
__device__ __forceinline__ f32x4 mfma16(f16x8 a, f16x8 b, f32x4 c) {
    return __builtin_amdgcn_mfma_f32_16x16x32_f16(a, b, c, 0, 0, 0);
}

__global__ void cast_f32_to_f16(const float* __restrict__ in,
                                f16* __restrict__ out, int n4) {
    int i = blockIdx.x * 256 + threadIdx.x;
    if (i < n4) {
        float4 v = reinterpret_cast<const float4*>(in)[i];
        f16 h0 = (f16)v.x, h1 = (f16)v.y, h2 = (f16)v.z, h3 = (f16)v.w;
        short4 pk;
        pk.x = __builtin_bit_cast(short, h0); pk.y = __builtin_bit_cast(short, h1);
        pk.z = __builtin_bit_cast(short, h2); pk.w = __builtin_bit_cast(short, h3);
        reinterpret_cast<short4*>(out)[i] = pk;
    }
}

// Wgh[l][16][1024] f16: rows 0-3 = Wg experts, rows 4-15 = 0.
__global__ void build_wgh(const float* __restrict__ Wg, f16* __restrict__ Wgh) {
    int i = blockIdx.x * 256 + threadIdx.x;          // < 3*16*1024
    int l = i >> 14, r = (i >> 10) & 15, k = i & 1023;
    f16 v = (f16)0.f;
    if (r < NEXP) v = (f16)Wg[(size_t)(l * NEXP + r) * DDIM + k];
    Wgh[i] = v;
}

__global__ __launch_bounds__(256, 2) void crossnet_fused(
    const float* __restrict__ x, float* __restrict__ out,
    const f16* __restrict__ Uh,   // [L][E][D][R]
    const f16* __restrict__ Vh,   // [L][256][1024]
    const f16* __restrict__ Ch,   // [L][E][64][64]
    const f16* __restrict__ Wgh,  // [L][16][1024]
    const float* __restrict__ bias)  // [L][1024]
{
    __shared__ f16  s_x0[BT][XPAD];      // x0 tile (f16), read-only after init
    __shared__ f16  s_xl[BT][XPAD];      // xl tile (f16), updated per layer
    __shared__ f16  s_v[BT][SPAD];       // v then p
    __shared__ float s_gl[4][BT][NEXP];  // per-wave gate partials
    __shared__ float s_g[BT][NEXP];      // softmax gate

    const int tid  = threadIdx.x;
    const int lane = tid & 63;
    const int wv   = tid >> 6;          // wave 0..3
    const int l16  = lane & 15;
    const int lhi  = lane >> 4;         // 0..3
    const int row0 = blockIdx.x * BT;

    // ---- stage x -> s_x0 (f16). 16 rows x 1024 cols, 8 f32 per thread-iter.
#pragma unroll
    for (int j = 0; j < 8; ++j) {
        int f   = tid + j * 256;        // 0..2047
        int row = f >> 7, seg = f & 127;
        const float* src = x + (size_t)(row0 + row) * DDIM + seg * 8;
        float4 a = *reinterpret_cast<const float4*>(src);
        float4 b = *reinterpret_cast<const float4*>(src + 4);
        f16x8 h;
        h[0]=(f16)a.x; h[1]=(f16)a.y; h[2]=(f16)a.z; h[3]=(f16)a.w;
        h[4]=(f16)b.x; h[5]=(f16)b.y; h[6]=(f16)b.z; h[7]=(f16)b.w;
        *reinterpret_cast<f16x8*>(&s_x0[row][seg * 8]) = h;
    }

#pragma unroll 1
    for (int l = 0; l < NLAY; ++l) {
        const f16 (*A)[XPAD] = (l == 0) ? (const f16(*)[XPAD])s_x0
                                        : (const f16(*)[XPAD])s_xl;
        const f16* Vl = Vh  + (size_t)l * NEXP * RLOW * DDIM;
        const f16* Ul = Uh  + (size_t)l * NEXP * DDIM * RLOW;
        const f16* Cl = Ch  + (size_t)l * NEXP * RLOW * RLOW;
        const f16* Wl = Wgh + (size_t)l * 16 * DDIM;
        const float* bl = bias + (size_t)l * DDIM;
        const int last = (l == NLAY - 1);

        __syncthreads();   // xl ready; s_v free

        // ===== GEMM-1: v = tanh(xl @ V^T), wave owns N-slice [wv*64, +64)
        //       + gate logit tile (wave-cyclic over k-tiles)
        f32x4 acc1[4], accg = {0.f, 0.f, 0.f, 0.f};
#pragma unroll
        for (int nt = 0; nt < 4; ++nt) acc1[nt] = (f32x4){0.f, 0.f, 0.f, 0.f};
        const f16* Vb[4];
#pragma unroll
        for (int nt = 0; nt < 4; ++nt)
            Vb[nt] = Vl + (size_t)(wv * 64 + nt * 16 + l16) * DDIM + lhi * 8;
        const f16* Wb = Wl + (size_t)l16 * DDIM + lhi * 8;

#pragma unroll 4
        for (int kt = 0; kt < 32; ++kt) {
            f16x8 af = *reinterpret_cast<const f16x8*>(&A[l16][kt * 32 + lhi * 8]);
#pragma unroll
            for (int nt = 0; nt < 4; ++nt)
                acc1[nt] = mfma16(af, *reinterpret_cast<const f16x8*>(Vb[nt] + kt * 32), acc1[nt]);
            if ((kt & 3) == wv)
                accg = mfma16(af, *reinterpret_cast<const f16x8*>(Wb + kt * 32), accg);
        }
#pragma unroll
        for (int nt = 0; nt < 4; ++nt)
#pragma unroll
            for (int r = 0; r < 4; ++r)
                s_v[lhi * 4 + r][wv * 64 + nt * 16 + l16] = (f16)ftanh(acc1[nt][r]);
        if (l16 < NEXP)
#pragma unroll
            for (int r = 0; r < 4; ++r) s_gl[wv][lhi * 4 + r][l16] = accg[r];
        __syncthreads();

        // ===== gate softmax: 64 threads, (row, e) = (tid>>2, tid&3)
        if (tid < 64) {
            int rr = tid >> 2, e = tid & 3;
            float lg = s_gl[0][rr][e] + s_gl[1][rr][e] + s_gl[2][rr][e] + s_gl[3][rr][e];
            float m = lg;
            m = fmaxf(m, __shfl_xor(m, 1));
            m = fmaxf(m, __shfl_xor(m, 2));
            float ex = __expf(lg - m);
            float sm = ex;
            sm += __shfl_xor(sm, 1);
            sm += __shfl_xor(sm, 2);
            s_g[rr][e] = ex / sm;
        }
        __syncthreads();

        // ===== GEMM-2: p = g_e * tanh(C_e @ v); wave wv = expert wv
        {
            f32x4 acc2[4];
#pragma unroll
            for (int nt = 0; nt < 4; ++nt) acc2[nt] = (f32x4){0.f, 0.f, 0.f, 0.f};
            const f16* Cb[4];
#pragma unroll
            for (int nt = 0; nt < 4; ++nt)
                Cb[nt] = Cl + (size_t)(wv * RLOW + nt * 16 + l16) * RLOW + lhi * 8;
#pragma unroll
            for (int kt = 0; kt < 2; ++kt) {
                f16x8 af = *reinterpret_cast<const f16x8*>(&s_v[l16][wv * 64 + kt * 32 + lhi * 8]);
#pragma unroll
                for (int nt = 0; nt < 4; ++nt)
                    acc2[nt] = mfma16(af, *reinterpret_cast<const f16x8*>(Cb[nt] + kt * 32), acc2[nt]);
            }
            // overwrite own v region with p (only this wave read it)
#pragma unroll
            for (int nt = 0; nt < 4; ++nt)
#pragma unroll
                for (int r = 0; r < 4; ++r) {
                    int m = lhi * 4 + r;
                    s_v[m][wv * 64 + nt * 16 + l16] =
                        (f16)(ftanh(acc2[nt][r]) * s_g[m][wv]);
                }
        }
        __syncthreads();

        // ===== GEMM-3: out = p @ U^T + epilogue; wave owns d in [wv*256,+256)
#pragma unroll 1
        for (int ps = 0; ps < 4; ++ps) {
            const int dbase = wv * 256 + ps * 64;
            f32x4 acc3[4];
#pragma unroll
            for (int nt = 0; nt < 4; ++nt) acc3[nt] = (f32x4){0.f, 0.f, 0.f, 0.f};
            const f16* Ub[4];
#pragma unroll
            for (int nt = 0; nt < 4; ++nt)
                Ub[nt] = Ul + (size_t)(dbase + nt * 16 + l16) * RLOW + lhi * 8;
#pragma unroll
            for (int kt = 0; kt < 8; ++kt) {
                f16x8 af = *reinterpret_cast<const f16x8*>(&s_v[l16][kt * 32 + lhi * 8]);
                const size_t eoff = (size_t)(kt >> 1) * DDIM * RLOW + (kt & 1) * 32;
#pragma unroll
                for (int nt = 0; nt < 4; ++nt)
                    acc3[nt] = mfma16(af, *reinterpret_cast<const f16x8*>(Ub[nt] + eoff), acc3[nt]);
            }
#pragma unroll
            for (int nt = 0; nt < 4; ++nt) {
                const int d = dbase + nt * 16 + l16;
                const float bd = bl[d];
#pragma unroll
                for (int r = 0; r < 4; ++r) {
                    const int m = lhi * 4 + r;
                    float y = fmaf(acc3[nt][r] + bd, (float)s_x0[m][d], (float)A[m][d]);
                    if (!last) s_xl[m][d] = (f16)ftanh(y);
                    else out[(size_t)(row0 + m) * DDIM + d] = y;
                }
            }
        }
    }
}

extern "C" void kernel_launch(void* const* d_in, const int* in_sizes, int n_in,
                              void* d_out, int out_size, void* d_ws, size_t ws_size,
                              hipStream_t stream)
{
    const float* x  = (const float*)d_in[0];
    const float* U  = (const float*)d_in[1];
    const float* V  = (const float*)d_in[2];
    const float* C  = (const float*)d_in[3];
    const float* Wg = (const float*)d_in[4];
    const float* bb = (const float*)d_in[5];
    float* out = (float*)d_out;

    const size_t sUV = (size_t)NEXP * DDIM * RLOW;          // 262144 per layer
    const size_t sC  = (size_t)NEXP * RLOW * RLOW;          // 16384  per layer
    const size_t sW  = (size_t)16 * DDIM;                   // 16384  per layer

    f16* Vh  = (f16*)d_ws;                                  // 1.5 MB
    f16* Uh  = Vh + NLAY * sUV;                             // 1.5 MB
    f16* Chh = Uh + NLAY * sUV;                             // 96 KB
    f16* Wgh = Chh + NLAY * sC;                             // 96 KB

    int n4v = (int)(NLAY * sUV / 4);
    cast_f32_to_f16<<<(n4v + 255) / 256, 256, 0, stream>>>(V, Vh, n4v);
    cast_f32_to_f16<<<(n4v + 255) / 256, 256, 0, stream>>>(U, Uh, n4v);
    int n4c = (int)(NLAY * sC / 4);
    cast_f32_to_f16<<<(n4c + 255) / 256, 256, 0, stream>>>(C, Chh, n4c);
    build_wgh<<<(int)(NLAY * sW / 256), 256, 0, stream>>>(Wg, Wgh);

    crossnet_fused<<<dim3(B_TOT / BT), dim3(256), 0, stream>>>(
        x, out, Uh, Vh, Chh, Wgh, bb);
}